// Round 2
// baseline (580.296 us; speedup 1.0000x reference)
//
#include <hip/hip_runtime.h>

typedef unsigned short u16;
typedef unsigned int u32;
typedef __attribute__((ext_vector_type(8))) short bf16x8;   // 8 bf16 = 4 VGPRs (MFMA A/B frag)
typedef __attribute__((ext_vector_type(4))) float f32x4;    // MFMA C/D frag

__device__ __forceinline__ u16 f2bf(float f) {
    u32 u = __float_as_uint(f);
    return (u16)((u + 0x7FFFu + ((u >> 16) & 1u)) >> 16);   // round-to-nearest-even
}
// XOR swizzle for 128x128 bf16 tile stored as uint4[2048]: row r (0..127), 16B-chunk c (0..15)
__device__ __forceinline__ int sw_idx(int r, int c) { return r * 16 + (c ^ (r & 15)); }

// ---------------------------------------------------------------------------
// Kernel A: sparse depthwise conv + bias + LayerNorm (all fp32).
// 1 wave/site: ballot-compact valid (idx,k) pairs (~8.4 of 343) into LDS,
// then gather-FMA; write LN output as bf16 (GEMM1 A-matrix).
// ---------------------------------------------------------------------------
__global__ __launch_bounds__(256) void dwln_k(
    const float* __restrict__ feats, const int* __restrict__ nb,
    const float* __restrict__ dw_w, const float* __restrict__ dw_b,
    const float* __restrict__ ln_g, const float* __restrict__ ln_b,
    u16* __restrict__ xln, int nsites)
{
    __shared__ int lists[4][344];
    const int w = threadIdx.x >> 6;
    const int lane = threadIdx.x & 63;
    const int site = blockIdx.x * 4 + w;
    if (site >= nsites) return;
    const int* row = nb + (size_t)site * 343;
    int cnt = 0;
    #pragma unroll
    for (int j = 0; j < 6; ++j) {
        const int k = j * 64 + lane;
        int idx = nsites;
        if (k < 343) idx = row[k];
        const bool valid = idx < nsites;
        const unsigned long long m = __ballot(valid);
        if (valid) {
            const int pos = (int)__popcll(m & ((1ull << lane) - 1ull));
            lists[w][cnt + pos] = idx | (k << 17);   // nsites < 2^17, k < 2^9
        }
        cnt += (int)__popcll(m);
    }
    float a0 = 0.f, a1 = 0.f;
    for (int e = 0; e < cnt; ++e) {
        const int p = lists[w][e];                    // LDS broadcast read
        const int idx = p & 0x1FFFF;
        const int k = p >> 17;
        const float2 fv = *(const float2*)(feats + (size_t)idx * 128 + lane * 2);
        const float2 wv = *(const float2*)(dw_w + (size_t)k * 128 + lane * 2);
        a0 += fv.x * wv.x;
        a1 += fv.y * wv.y;
    }
    const float2 bv = *(const float2*)(dw_b + lane * 2);
    a0 += bv.x;
    a1 += bv.y;
    // LayerNorm over 128 channels (2 per lane), wave-wide butterfly reduce
    float s = a0 + a1, ss = a0 * a0 + a1 * a1;
    #pragma unroll
    for (int off = 32; off > 0; off >>= 1) {
        s += __shfl_xor(s, off, 64);
        ss += __shfl_xor(ss, off, 64);
    }
    const float mean = s * (1.f / 128.f);
    const float var = ss * (1.f / 128.f) - mean * mean;
    const float rstd = rsqrtf(fmaxf(var, 0.f) + 1e-6f);
    const float2 gv = *(const float2*)(ln_g + lane * 2);
    const float2 lbv = *(const float2*)(ln_b + lane * 2);
    const float y0 = (a0 - mean) * rstd * gv.x + lbv.x;
    const float y1 = (a1 - mean) * rstd * gv.y + lbv.y;
    *(u32*)(xln + (size_t)site * 128 + lane * 2) = (u32)f2bf(y0) | ((u32)f2bf(y1) << 16);
}

// ---------------------------------------------------------------------------
// w1 fp32 [128,512] -> w1t bf16 [512,128] (B^T layout for MFMA B-frag reads)
// ---------------------------------------------------------------------------
__global__ __launch_bounds__(256) void transpose_w1_k(
    const float* __restrict__ w1, u16* __restrict__ w1t)
{
    const int e = blockIdx.x * 256 + threadIdx.x;    // 65536 total
    const int n = e >> 7, k = e & 127;
    w1t[e] = f2bf(w1[k * 512 + n]);
}

// ---------------------------------------------------------------------------
// Kernel B: h = gelu(xln @ w1 + b1)  [N,512] bf16  + per-channel sum(h^2)
// 128x128 tile per block, K=128 single stage, 4 waves in 2x2.
// ---------------------------------------------------------------------------
__global__ __launch_bounds__(256) void gemm1_k(
    const u16* __restrict__ xln, const u16* __restrict__ w1t,
    const float* __restrict__ b1, u16* __restrict__ h,
    float* __restrict__ gx_sq, int nsites)
{
    __shared__ uint4 sA[2048];   // 32 KB
    __shared__ uint4 sB[2048];   // 32 KB
    const int t = threadIdx.x;
    const int m0 = blockIdx.x * 128;
    const int n0 = blockIdx.y * 128;
    #pragma unroll
    for (int it = 0; it < 8; ++it) {
        const int e = it * 256 + t;
        const int r = e >> 4, c = e & 15;
        uint4 va = {0u, 0u, 0u, 0u};
        const int rowg = m0 + r;
        if (rowg < nsites) va = *(const uint4*)(xln + (size_t)rowg * 128 + c * 8);
        sA[sw_idx(r, c)] = va;
        sB[sw_idx(r, c)] = *(const uint4*)(w1t + (size_t)(n0 + r) * 128 + c * 8);
    }
    __syncthreads();
    const int lane = t & 63;
    const int w = t >> 6;
    const int wm = (w >> 1) * 64, wn = (w & 1) * 64;
    const int l15 = lane & 15, quad = lane >> 4;
    f32x4 acc[4][4];
    #pragma unroll
    for (int i = 0; i < 4; ++i)
        #pragma unroll
        for (int j = 0; j < 4; ++j) acc[i][j] = f32x4{0.f, 0.f, 0.f, 0.f};
    #pragma unroll
    for (int kk = 0; kk < 128; kk += 32) {
        const int cq = (kk >> 3) + quad;
        bf16x8 a[4], b[4];
        #pragma unroll
        for (int mt = 0; mt < 4; ++mt) a[mt] = *(const bf16x8*)&sA[sw_idx(wm + mt * 16 + l15, cq)];
        #pragma unroll
        for (int nt = 0; nt < 4; ++nt) b[nt] = *(const bf16x8*)&sB[sw_idx(wn + nt * 16 + l15, cq)];
        #pragma unroll
        for (int mt = 0; mt < 4; ++mt)
            #pragma unroll
            for (int nt = 0; nt < 4; ++nt)
                acc[mt][nt] = __builtin_amdgcn_mfma_f32_16x16x32_bf16(a[mt], b[nt], acc[mt][nt], 0, 0, 0);
    }
    __syncthreads();                       // all frag reads of sA done; reuse as reduction buffer
    float* s_red = (float*)sA;
    if (t < 128) s_red[t] = 0.f;
    __syncthreads();
    float ssl[4] = {0.f, 0.f, 0.f, 0.f};
    float bias[4]; int col[4];
    #pragma unroll
    for (int nt = 0; nt < 4; ++nt) {
        col[nt] = n0 + wn + nt * 16 + l15;
        bias[nt] = b1[col[nt]];
    }
    #pragma unroll
    for (int mt = 0; mt < 4; ++mt) {
        const int rbase = m0 + wm + mt * 16 + quad * 4;
        #pragma unroll
        for (int nt = 0; nt < 4; ++nt) {
            #pragma unroll
            for (int rg = 0; rg < 4; ++rg) {
                const int rowg = rbase + rg;
                if (rowg < nsites) {
                    float v = acc[mt][nt][rg] + bias[nt];
                    v = 0.5f * v * (1.f + erff(v * 0.70710678118654752f));  // exact gelu
                    h[(size_t)rowg * 512 + col[nt]] = f2bf(v);
                    ssl[nt] += v * v;
                }
            }
        }
    }
    #pragma unroll
    for (int nt = 0; nt < 4; ++nt) atomicAdd(&s_red[wn + nt * 16 + l15], ssl[nt]);
    __syncthreads();
    if (t < 128) atomicAdd(&gx_sq[n0 + t], s_red[t]);
}

// ---------------------------------------------------------------------------
// Kernel C: GRN prep. nx from gx_sq; fold GRN scale into w2 rows (-> w2t bf16,
// B^T layout [128 dc][512 c]) and grn_b into bias: b_eff = b2 + grn_b @ w2.
// ---------------------------------------------------------------------------
__global__ __launch_bounds__(512) void grn_prep_k(
    const float* __restrict__ gx_sq, const float* __restrict__ grn_g,
    const float* __restrict__ grn_b, const float* __restrict__ w2,
    const float* __restrict__ b2, u16* __restrict__ w2t, float* __restrict__ b_eff)
{
    __shared__ float s_scale[512];
    __shared__ float red[512];
    const int t = threadIdx.x;
    const float g = sqrtf(gx_sq[t]);
    red[t] = g;
    __syncthreads();
    #pragma unroll
    for (int off = 256; off > 0; off >>= 1) {
        if (t < off) red[t] += red[t + off];
        __syncthreads();
    }
    const float mean = red[0] * (1.f / 512.f);
    const float nx = g / (mean + 1e-6f);
    s_scale[t] = grn_g[t] * nx + 1.f;
    __syncthreads();
    for (int dc = 0; dc < 128; ++dc)       // thread t = channel c
        w2t[(size_t)dc * 512 + t] = f2bf(s_scale[t] * w2[(size_t)t * 128 + dc]);
    if (t < 128) {
        float be = b2[t];
        for (int c = 0; c < 512; ++c) be += grn_b[c] * w2[(size_t)c * 128 + t];
        b_eff[t] = be;
    }
}

// ---------------------------------------------------------------------------
// Kernel D: out = feats + h_scaled @ w2 + b_eff (fp32 out).  M-tile 128,
// N=128, K=512 in 4 staged chunks of 128.
// ---------------------------------------------------------------------------
__global__ __launch_bounds__(256) void gemm2_k(
    const u16* __restrict__ h, const u16* __restrict__ w2t,
    const float* __restrict__ b_eff, const float* __restrict__ feats,
    float* __restrict__ out, int nsites)
{
    __shared__ uint4 sA[2048];
    __shared__ uint4 sB[2048];
    const int t = threadIdx.x;
    const int m0 = blockIdx.x * 128;
    const int lane = t & 63;
    const int w = t >> 6;
    const int wm = (w >> 1) * 64, wn = (w & 1) * 64;
    const int l15 = lane & 15, quad = lane >> 4;
    f32x4 acc[4][4];
    #pragma unroll
    for (int i = 0; i < 4; ++i)
        #pragma unroll
        for (int j = 0; j < 4; ++j) acc[i][j] = f32x4{0.f, 0.f, 0.f, 0.f};
    for (int kc = 0; kc < 4; ++kc) {
        const int kbase = kc * 128;
        __syncthreads();
        #pragma unroll
        for (int it = 0; it < 8; ++it) {
            const int e = it * 256 + t;
            const int r = e >> 4, c = e & 15;
            uint4 va = {0u, 0u, 0u, 0u};
            const int rowg = m0 + r;
            if (rowg < nsites) va = *(const uint4*)(h + (size_t)rowg * 512 + kbase + c * 8);
            sA[sw_idx(r, c)] = va;
            sB[sw_idx(r, c)] = *(const uint4*)(w2t + (size_t)r * 512 + kbase + c * 8);
        }
        __syncthreads();
        #pragma unroll
        for (int kk = 0; kk < 128; kk += 32) {
            const int cq = (kk >> 3) + quad;
            bf16x8 a[4], b[4];
            #pragma unroll
            for (int mt = 0; mt < 4; ++mt) a[mt] = *(const bf16x8*)&sA[sw_idx(wm + mt * 16 + l15, cq)];
            #pragma unroll
            for (int nt = 0; nt < 4; ++nt) b[nt] = *(const bf16x8*)&sB[sw_idx(wn + nt * 16 + l15, cq)];
            #pragma unroll
            for (int mt = 0; mt < 4; ++mt)
                #pragma unroll
                for (int nt = 0; nt < 4; ++nt)
                    acc[mt][nt] = __builtin_amdgcn_mfma_f32_16x16x32_bf16(a[mt], b[nt], acc[mt][nt], 0, 0, 0);
        }
    }
    float be[4]; int col[4];
    #pragma unroll
    for (int nt = 0; nt < 4; ++nt) {
        col[nt] = wn + nt * 16 + l15;
        be[nt] = b_eff[col[nt]];
    }
    #pragma unroll
    for (int mt = 0; mt < 4; ++mt) {
        const int rbase = m0 + wm + mt * 16 + quad * 4;
        #pragma unroll
        for (int nt = 0; nt < 4; ++nt) {
            #pragma unroll
            for (int rg = 0; rg < 4; ++rg) {
                const int rowg = rbase + rg;
                if (rowg < nsites) {
                    const float v = acc[mt][nt][rg] + be[nt] +
                                    feats[(size_t)rowg * 128 + col[nt]];
                    out[(size_t)rowg * 128 + col[nt]] = v;
                }
            }
        }
    }
}

// ---------------------------------------------------------------------------
extern "C" void kernel_launch(void* const* d_in, const int* in_sizes, int n_in,
                              void* d_out, int out_size, void* d_ws, size_t ws_size,
                              hipStream_t stream) {
    const float* feats = (const float*)d_in[0];    // [N,128] f32
    const int* nb      = (const int*)d_in[1];      // [N,343] int32
    const float* dw_w  = (const float*)d_in[2];    // [343,128] f32
    const float* dw_b  = (const float*)d_in[3];    // [128]
    const float* ln_g  = (const float*)d_in[4];    // [128]
    const float* ln_b  = (const float*)d_in[5];    // [128]
    const float* w1    = (const float*)d_in[6];    // [128,512]
    const float* b1    = (const float*)d_in[7];    // [512]
    const float* grn_g = (const float*)d_in[8];    // [512]
    const float* grn_b = (const float*)d_in[9];    // [512]
    const float* w2    = (const float*)d_in[10];   // [512,128]
    const float* b2    = (const float*)d_in[11];   // [128]
    float* out = (float*)d_out;
    const int nsites = in_sizes[0] / 128;

    char* ws = (char*)d_ws;
    size_t off = 0;
    u16* xln = (u16*)(ws + off);  off += (((size_t)nsites * 128 * 2) + 255) & ~(size_t)255;
    u16* h   = (u16*)(ws + off);  off += (((size_t)nsites * 512 * 2) + 255) & ~(size_t)255;
    u16* w1t = (u16*)(ws + off);  off += 512 * 128 * 2;
    u16* w2t = (u16*)(ws + off);  off += 128 * 512 * 2;
    float* gx_sq = (float*)(ws + off); off += 512 * 4;
    float* b_eff = (float*)(ws + off); off += 128 * 4;

    hipMemsetAsync(gx_sq, 0, 512 * sizeof(float), stream);
    transpose_w1_k<<<256, 256, 0, stream>>>(w1, w1t);
    dwln_k<<<(nsites + 3) / 4, 256, 0, stream>>>(feats, nb, dw_w, dw_b, ln_g, ln_b, xln, nsites);
    const int mblocks = (nsites + 127) / 128;
    gemm1_k<<<dim3(mblocks, 4), 256, 0, stream>>>(xln, w1t, b1, h, gx_sq, nsites);
    grn_prep_k<<<1, 512, 0, stream>>>(gx_sq, grn_g, grn_b, w2, b2, w2t, b_eff);
    gemm2_k<<<mblocks, 256, 0, stream>>>(h, w2t, b_eff, feats, out, nsites);
}

// Round 3
// 526.123 us; speedup vs baseline: 1.1030x; 1.1030x over previous
//
#include <hip/hip_runtime.h>

typedef unsigned short u16;
typedef unsigned int u32;
typedef __attribute__((ext_vector_type(8))) short bf16x8;   // 8 bf16 = 4 VGPRs (MFMA A/B frag)
typedef __attribute__((ext_vector_type(4))) float f32x4;    // MFMA C/D frag

__device__ __forceinline__ u16 f2bf(float f) {
    u32 u = __float_as_uint(f);
    return (u16)((u + 0x7FFFu + ((u >> 16) & 1u)) >> 16);   // round-to-nearest-even
}
// XOR swizzle for 128x128 bf16 tile stored as uint4[2048]: row r (0..127), 16B-chunk c (0..15)
__device__ __forceinline__ int sw_idx(int r, int c) { return r * 16 + (c ^ (r & 15)); }

// fast GELU: tanh approximation, ~15 VALU inst (vs ~70 for libm erff path)
__device__ __forceinline__ float fast_gelu(float x) {
    const float x3 = x * x * x;
    const float y2 = 1.5957691216057308f * (x + 0.044715f * x3);   // 2*0.79788456*(x+c x^3)
    const float u = __expf(fminf(y2, 80.f));                        // e^{2y}, overflow-capped
    const float th = (u - 1.f) / (u + 1.f);                         // tanh(y)
    return 0.5f * x * (1.f + th);
}

// ---------------------------------------------------------------------------
// Kernel A: sparse depthwise conv + bias + LayerNorm (fp32 compute).
// 1 wave/site: ballot-compact valid (idx,k) pairs (~8.4 of 343) into LDS,
// then gather-FMA (unrolled x2); write LN output as bf16 (GEMM1 A-matrix).
// ---------------------------------------------------------------------------
__global__ __launch_bounds__(256) void dwln_k(
    const float* __restrict__ feats, const int* __restrict__ nb,
    const float* __restrict__ dw_w, const float* __restrict__ dw_b,
    const float* __restrict__ ln_g, const float* __restrict__ ln_b,
    u16* __restrict__ xln, int nsites)
{
    __shared__ int lists[4][344];
    const int w = threadIdx.x >> 6;
    const int lane = threadIdx.x & 63;
    const int site = blockIdx.x * 4 + w;
    if (site >= nsites) return;
    const int* row = nb + (size_t)site * 343;
    int cnt = 0;
    #pragma unroll
    for (int j = 0; j < 6; ++j) {
        const int k = j * 64 + lane;
        int idx = nsites;
        if (k < 343) idx = row[k];
        const bool valid = idx < nsites;
        const unsigned long long m = __ballot(valid);
        if (valid) {
            const int pos = (int)__popcll(m & ((1ull << lane) - 1ull));
            lists[w][cnt + pos] = idx | (k << 17);   // nsites < 2^17, k < 2^9
        }
        cnt += (int)__popcll(m);
    }
    float a0 = 0.f, a1 = 0.f;
    int e = 0;
    for (; e + 1 < cnt; e += 2) {
        const int p0 = lists[w][e];
        const int p1 = lists[w][e + 1];
        const float2 f0 = *(const float2*)(feats + (size_t)(p0 & 0x1FFFF) * 128 + lane * 2);
        const float2 w0 = *(const float2*)(dw_w + (size_t)(p0 >> 17) * 128 + lane * 2);
        const float2 f1 = *(const float2*)(feats + (size_t)(p1 & 0x1FFFF) * 128 + lane * 2);
        const float2 w1v = *(const float2*)(dw_w + (size_t)(p1 >> 17) * 128 + lane * 2);
        a0 += f0.x * w0.x + f1.x * w1v.x;
        a1 += f0.y * w0.y + f1.y * w1v.y;
    }
    if (e < cnt) {
        const int p0 = lists[w][e];
        const float2 f0 = *(const float2*)(feats + (size_t)(p0 & 0x1FFFF) * 128 + lane * 2);
        const float2 w0 = *(const float2*)(dw_w + (size_t)(p0 >> 17) * 128 + lane * 2);
        a0 += f0.x * w0.x;
        a1 += f0.y * w0.y;
    }
    const float2 bv = *(const float2*)(dw_b + lane * 2);
    a0 += bv.x;
    a1 += bv.y;
    float s = a0 + a1, ss = a0 * a0 + a1 * a1;
    #pragma unroll
    for (int off = 32; off > 0; off >>= 1) {
        s += __shfl_xor(s, off, 64);
        ss += __shfl_xor(ss, off, 64);
    }
    const float mean = s * (1.f / 128.f);
    const float var = ss * (1.f / 128.f) - mean * mean;
    const float rstd = rsqrtf(fmaxf(var, 0.f) + 1e-6f);
    const float2 gv = *(const float2*)(ln_g + lane * 2);
    const float2 lbv = *(const float2*)(ln_b + lane * 2);
    const float y0 = (a0 - mean) * rstd * gv.x + lbv.x;
    const float y1 = (a1 - mean) * rstd * gv.y + lbv.y;
    *(u32*)(xln + (size_t)site * 128 + lane * 2) = (u32)f2bf(y0) | ((u32)f2bf(y1) << 16);
}

// ---------------------------------------------------------------------------
// w1 fp32 [128,512] -> w1t bf16 [512,128] (B^T layout for MFMA B-frag reads)
// ---------------------------------------------------------------------------
__global__ __launch_bounds__(256) void transpose_w1_k(
    const float* __restrict__ w1, u16* __restrict__ w1t)
{
    const int e = blockIdx.x * 256 + threadIdx.x;    // 65536 total
    const int n = e >> 7, k = e & 127;
    w1t[e] = f2bf(w1[k * 512 + n]);
}

// ---------------------------------------------------------------------------
// Kernel B: h = gelu(xln @ w1 + b1)  [N,512] bf16  + per-channel sum(h^2).
// One block per 128-row M-tile; A staged ONCE in 32 KB LDS; loop over 4
// N-tiles barrier-free with B frags read directly from L2-resident w1t.
// ---------------------------------------------------------------------------
__global__ __launch_bounds__(256, 3) void gemm1_k(
    const u16* __restrict__ xln, const u16* __restrict__ w1t,
    const float* __restrict__ b1, u16* __restrict__ h,
    float* __restrict__ gx_sq, int nsites)
{
    __shared__ uint4 sA[2048];   // 32 KB
    __shared__ float s_red[512];
    const int t = threadIdx.x;
    const int m0 = blockIdx.x * 128;
    #pragma unroll
    for (int it = 0; it < 8; ++it) {
        const int e = it * 256 + t;
        const int r = e >> 4, c = e & 15;
        uint4 va = {0u, 0u, 0u, 0u};
        const int rowg = m0 + r;
        if (rowg < nsites) va = *(const uint4*)(xln + (size_t)rowg * 128 + c * 8);
        sA[sw_idx(r, c)] = va;
    }
    s_red[t] = 0.f;
    s_red[t + 256] = 0.f;
    __syncthreads();
    const int lane = t & 63;
    const int w = t >> 6;
    const int wm = (w >> 1) * 64, wn = (w & 1) * 64;
    const int l15 = lane & 15, quad = lane >> 4;
    for (int j = 0; j < 4; ++j) {
        const int n0 = j * 128;
        f32x4 acc[4][4];
        #pragma unroll
        for (int i = 0; i < 4; ++i)
            #pragma unroll
            for (int jj = 0; jj < 4; ++jj) acc[i][jj] = f32x4{0.f, 0.f, 0.f, 0.f};
        #pragma unroll
        for (int kk = 0; kk < 4; ++kk) {
            const int cq = kk * 4 + quad;
            bf16x8 a[4], b[4];
            #pragma unroll
            for (int mt = 0; mt < 4; ++mt) a[mt] = *(const bf16x8*)&sA[sw_idx(wm + mt * 16 + l15, cq)];
            #pragma unroll
            for (int nt = 0; nt < 4; ++nt)
                b[nt] = *(const bf16x8*)(w1t + (size_t)(n0 + wn + nt * 16 + l15) * 128 + cq * 8);
            #pragma unroll
            for (int mt = 0; mt < 4; ++mt)
                #pragma unroll
                for (int nt = 0; nt < 4; ++nt)
                    acc[mt][nt] = __builtin_amdgcn_mfma_f32_16x16x32_bf16(a[mt], b[nt], acc[mt][nt], 0, 0, 0);
        }
        float ssl[4] = {0.f, 0.f, 0.f, 0.f};
        float bias[4]; int col[4];
        #pragma unroll
        for (int nt = 0; nt < 4; ++nt) {
            col[nt] = n0 + wn + nt * 16 + l15;
            bias[nt] = b1[col[nt]];
        }
        #pragma unroll
        for (int mt = 0; mt < 4; ++mt) {
            const int rbase = m0 + wm + mt * 16 + quad * 4;
            #pragma unroll
            for (int nt = 0; nt < 4; ++nt) {
                #pragma unroll
                for (int rg = 0; rg < 4; ++rg) {
                    const int rowg = rbase + rg;
                    if (rowg < nsites) {
                        const float v = fast_gelu(acc[mt][nt][rg] + bias[nt]);
                        h[(size_t)rowg * 512 + col[nt]] = f2bf(v);
                        ssl[nt] += v * v;
                    }
                }
            }
        }
        #pragma unroll
        for (int nt = 0; nt < 4; ++nt) atomicAdd(&s_red[col[nt]], ssl[nt]);
    }
    __syncthreads();
    atomicAdd(&gx_sq[t], s_red[t]);
    atomicAdd(&gx_sq[t + 256], s_red[t + 256]);
}

// ---------------------------------------------------------------------------
// Kernel C1: GRN scale + effective bias (one block, cooperative).
// scale[c] = grn_g[c]*nx[c] + 1;  b_eff = b2 + grn_b @ w2.
// ---------------------------------------------------------------------------
__global__ __launch_bounds__(512) void grn_scale_k(
    const float* __restrict__ gx_sq, const float* __restrict__ grn_g,
    const float* __restrict__ grn_b, const float* __restrict__ w2,
    const float* __restrict__ b2, float* __restrict__ scale, float* __restrict__ b_eff)
{
    __shared__ float red[512];
    __shared__ float redb[512];
    const int t = threadIdx.x;
    const float g = sqrtf(gx_sq[t]);
    red[t] = g;
    __syncthreads();
    #pragma unroll
    for (int off = 256; off > 0; off >>= 1) {
        if (t < off) red[t] += red[t + off];
        __syncthreads();
    }
    const float mean = red[0] * (1.f / 512.f);
    scale[t] = grn_g[t] * (g / (mean + 1e-6f)) + 1.f;
    // b_eff reduction: thread (grp, dc) sums grn_b[c]*w2[c,dc] over c in grp's range
    const int dc = t & 127, grp = t >> 7;
    float p = 0.f;
    for (int i = 0; i < 128; ++i) {
        const int c = grp * 128 + i;
        p += grn_b[c] * w2[(size_t)c * 128 + dc];
    }
    redb[t] = p;
    __syncthreads();
    if (t < 128) b_eff[t] = b2[t] + redb[t] + redb[t + 128] + redb[t + 256] + redb[t + 384];
}

// ---------------------------------------------------------------------------
// Kernel C2: w2t[dc][c] = bf16(scale[c] * w2[c][dc])  (coalesced writes)
// ---------------------------------------------------------------------------
__global__ __launch_bounds__(256) void w2t_k(
    const float* __restrict__ scale, const float* __restrict__ w2,
    u16* __restrict__ w2t)
{
    const int e = blockIdx.x * 256 + threadIdx.x;    // 65536
    const int c = e & 511, dc = e >> 9;
    w2t[e] = f2bf(scale[c] * w2[(size_t)c * 128 + dc]);
}

// ---------------------------------------------------------------------------
// Kernel D: out = feats + h_scaled @ w2 + b_eff (fp32 out).  M-tile 128,
// N=128, K=512 in 4 staged 32 KB chunks; B frags from L2-resident w2t.
// ---------------------------------------------------------------------------
__global__ __launch_bounds__(256, 3) void gemm2_k(
    const u16* __restrict__ h, const u16* __restrict__ w2t,
    const float* __restrict__ b_eff, const float* __restrict__ feats,
    float* __restrict__ out, int nsites)
{
    __shared__ uint4 sA[2048];   // 32 KB
    const int t = threadIdx.x;
    const int m0 = blockIdx.x * 128;
    const int lane = t & 63;
    const int w = t >> 6;
    const int wm = (w >> 1) * 64, wn = (w & 1) * 64;
    const int l15 = lane & 15, quad = lane >> 4;
    f32x4 acc[4][4];
    #pragma unroll
    for (int i = 0; i < 4; ++i)
        #pragma unroll
        for (int j = 0; j < 4; ++j) acc[i][j] = f32x4{0.f, 0.f, 0.f, 0.f};
    for (int kc = 0; kc < 4; ++kc) {
        const int kbase = kc * 128;
        if (kc) __syncthreads();
        #pragma unroll
        for (int it = 0; it < 8; ++it) {
            const int e = it * 256 + t;
            const int r = e >> 4, c = e & 15;
            uint4 va = {0u, 0u, 0u, 0u};
            const int rowg = m0 + r;
            if (rowg < nsites) va = *(const uint4*)(h + (size_t)rowg * 512 + kbase + c * 8);
            sA[sw_idx(r, c)] = va;
        }
        __syncthreads();
        #pragma unroll
        for (int kk = 0; kk < 4; ++kk) {
            const int cq = kk * 4 + quad;
            bf16x8 a[4], b[4];
            #pragma unroll
            for (int mt = 0; mt < 4; ++mt) a[mt] = *(const bf16x8*)&sA[sw_idx(wm + mt * 16 + l15, cq)];
            #pragma unroll
            for (int nt = 0; nt < 4; ++nt)
                b[nt] = *(const bf16x8*)(w2t + (size_t)(wn + nt * 16 + l15) * 512 + kbase + cq * 8);
            #pragma unroll
            for (int mt = 0; mt < 4; ++mt)
                #pragma unroll
                for (int nt = 0; nt < 4; ++nt)
                    acc[mt][nt] = __builtin_amdgcn_mfma_f32_16x16x32_bf16(a[mt], b[nt], acc[mt][nt], 0, 0, 0);
        }
    }
    float be[4]; int col[4];
    #pragma unroll
    for (int nt = 0; nt < 4; ++nt) {
        col[nt] = wn + nt * 16 + l15;
        be[nt] = b_eff[col[nt]];
    }
    #pragma unroll
    for (int mt = 0; mt < 4; ++mt) {
        const int rbase = m0 + wm + mt * 16 + quad * 4;
        #pragma unroll
        for (int nt = 0; nt < 4; ++nt) {
            #pragma unroll
            for (int rg = 0; rg < 4; ++rg) {
                const int rowg = rbase + rg;
                if (rowg < nsites) {
                    out[(size_t)rowg * 128 + col[nt]] =
                        acc[mt][nt][rg] + be[nt] + feats[(size_t)rowg * 128 + col[nt]];
                }
            }
        }
    }
}

// ---------------------------------------------------------------------------
extern "C" void kernel_launch(void* const* d_in, const int* in_sizes, int n_in,
                              void* d_out, int out_size, void* d_ws, size_t ws_size,
                              hipStream_t stream) {
    const float* feats = (const float*)d_in[0];    // [N,128] f32
    const int* nb      = (const int*)d_in[1];      // [N,343] int32
    const float* dw_w  = (const float*)d_in[2];    // [343,128] f32
    const float* dw_b  = (const float*)d_in[3];    // [128]
    const float* ln_g  = (const float*)d_in[4];    // [128]
    const float* ln_b  = (const float*)d_in[5];    // [128]
    const float* w1    = (const float*)d_in[6];    // [128,512]
    const float* b1    = (const float*)d_in[7];    // [512]
    const float* grn_g = (const float*)d_in[8];    // [512]
    const float* grn_b = (const float*)d_in[9];    // [512]
    const float* w2    = (const float*)d_in[10];   // [512,128]
    const float* b2    = (const float*)d_in[11];   // [128]
    float* out = (float*)d_out;
    const int nsites = in_sizes[0] / 128;

    char* ws = (char*)d_ws;
    size_t off = 0;
    u16* xln = (u16*)(ws + off);  off += (((size_t)nsites * 128 * 2) + 255) & ~(size_t)255;
    u16* h   = (u16*)(ws + off);  off += (((size_t)nsites * 512 * 2) + 255) & ~(size_t)255;
    u16* w1t = (u16*)(ws + off);  off += 512 * 128 * 2;
    u16* w2t = (u16*)(ws + off);  off += 128 * 512 * 2;
    float* gx_sq = (float*)(ws + off); off += 512 * 4;
    float* scale = (float*)(ws + off); off += 512 * 4;
    float* b_eff = (float*)(ws + off); off += 128 * 4;

    hipMemsetAsync(gx_sq, 0, 512 * sizeof(float), stream);
    transpose_w1_k<<<256, 256, 0, stream>>>(w1, w1t);
    dwln_k<<<(nsites + 3) / 4, 256, 0, stream>>>(feats, nb, dw_w, dw_b, ln_g, ln_b, xln, nsites);
    const int mblocks = (nsites + 127) / 128;
    gemm1_k<<<mblocks, 256, 0, stream>>>(xln, w1t, b1, h, gx_sq, nsites);
    grn_scale_k<<<1, 512, 0, stream>>>(gx_sq, grn_g, grn_b, w2, b2, scale, b_eff);
    w2t_k<<<256, 256, 0, stream>>>(scale, w2, w2t);
    gemm2_k<<<mblocks, 256, 0, stream>>>(h, w2t, b_eff, feats, out, nsites);
}

// Round 4
// 511.688 us; speedup vs baseline: 1.1341x; 1.0282x over previous
//
#include <hip/hip_runtime.h>

typedef unsigned short u16;
typedef unsigned int u32;
typedef __attribute__((ext_vector_type(8))) short bf16x8;   // 8 bf16 = 4 VGPRs (MFMA A/B frag)
typedef __attribute__((ext_vector_type(4))) float f32x4;    // MFMA C/D frag

__device__ __forceinline__ u16 f2bf(float f) {
    u32 u = __float_as_uint(f);
    return (u16)((u + 0x7FFFu + ((u >> 16) & 1u)) >> 16);   // round-to-nearest-even
}
// XOR swizzle for 128x128 bf16 tile stored as uint4[2048]: row r (0..127), 16B-chunk c (0..15)
__device__ __forceinline__ int sw_idx(int r, int c) { return r * 16 + (c ^ (r & 15)); }

// fast GELU: tanh approximation (~12 VALU inst; |err| vs exact erf-gelu ~3e-3)
__device__ __forceinline__ float fast_gelu(float x) {
    const float x3 = x * x * x;
    const float y2 = 1.5957691216057308f * (x + 0.044715f * x3);   // 2*0.79788456*(x+c x^3)
    const float u = __expf(fminf(y2, 80.f));                        // e^{2y}, overflow-capped
    const float th = (u - 1.f) / (u + 1.f);                         // tanh(y)
    return 0.5f * x * (1.f + th);
}

// ---------------------------------------------------------------------------
// Prep: cast feats fp32 -> bf16 (gather traffic halves; 25.6 MB is L3-hot)
// ---------------------------------------------------------------------------
__global__ __launch_bounds__(256) void cast_feats_k(
    const float* __restrict__ src, u16* __restrict__ dst, int n4)
{
    const int e = blockIdx.x * 256 + threadIdx.x;
    if (e >= n4) return;
    const float4 v = *(const float4*)(src + (size_t)e * 4);
    uint2 o;
    o.x = (u32)f2bf(v.x) | ((u32)f2bf(v.y) << 16);
    o.y = (u32)f2bf(v.z) | ((u32)f2bf(v.w) << 16);
    *(uint2*)(dst + (size_t)e * 4) = o;
}

// ---------------------------------------------------------------------------
// Kernel A: sparse depthwise conv + bias + LayerNorm.
// 1 wave/site. Scan: all 6 idx loads issued upfront (independent), then pure
// VALU compaction (per-lane count -> wave prefix -> LDS scatter).
// Gather: 8-deep load batching (16 outstanding loads/wave) over bf16 rows.
// ---------------------------------------------------------------------------
__global__ __launch_bounds__(256) void dwln_k(
    const u16* __restrict__ featsb, const int* __restrict__ nb,
    const u16* __restrict__ dwwb, const float* __restrict__ dw_b,
    const float* __restrict__ ln_g, const float* __restrict__ ln_b,
    u16* __restrict__ xln, int nsites)
{
    __shared__ int lists[4][348];
    const int w = threadIdx.x >> 6;
    const int lane = threadIdx.x & 63;
    const int site = blockIdx.x * 4 + w;
    if (site >= nsites) return;
    const int* row = nb + (size_t)site * 343;
    // 343 = 5*64 + 23: five full coalesced dword rounds + 23-lane tail
    int idxs[6];
    #pragma unroll
    for (int j = 0; j < 5; ++j) idxs[j] = row[lane + j * 64];
    idxs[5] = (lane < 23) ? row[320 + lane] : nsites;
    int c = 0;
    #pragma unroll
    for (int i = 0; i < 6; ++i) c += (idxs[i] < nsites) ? 1 : 0;
    // exclusive wave prefix-sum of valid counts
    int pre = c;
    #pragma unroll
    for (int off = 1; off < 64; off <<= 1) {
        const int v = __shfl_up(pre, off, 64);
        if (lane >= off) pre += v;
    }
    const int cnt = __shfl(pre, 63, 64);
    pre -= c;
    #pragma unroll
    for (int i = 0; i < 6; ++i) {
        if (idxs[i] < nsites) {
            lists[w][pre++] = idxs[i] | ((lane + i * 64) << 17);  // k = lane + i*64; idx < 2^17
        }
    }
    // gather-FMA, 8 entries per batch (loads issued before consumption)
    float a0 = 0.f, a1 = 0.f;
    for (int base = 0; base < cnt; base += 8) {
        u32 fv[8], wv[8];
        const int mlen = cnt - base;
        #pragma unroll
        for (int i = 0; i < 8; ++i) {
            if (i < mlen) {
                const int p = lists[w][base + i];
                fv[i] = *(const u32*)(featsb + (size_t)(p & 0x1FFFF) * 128 + lane * 2);
                wv[i] = *(const u32*)(dwwb + (size_t)(p >> 17) * 128 + lane * 2);
            } else { fv[i] = 0u; wv[i] = 0u; }
        }
        #pragma unroll
        for (int i = 0; i < 8; ++i) {
            const float f0 = __uint_as_float(fv[i] << 16);
            const float f1 = __uint_as_float(fv[i] & 0xFFFF0000u);
            const float g0 = __uint_as_float(wv[i] << 16);
            const float g1 = __uint_as_float(wv[i] & 0xFFFF0000u);
            a0 += f0 * g0;
            a1 += f1 * g1;
        }
    }
    const float2 bv = *(const float2*)(dw_b + lane * 2);
    a0 += bv.x;
    a1 += bv.y;
    // LayerNorm over 128 channels (2 per lane), wave butterfly reduce
    float s = a0 + a1, ss = a0 * a0 + a1 * a1;
    #pragma unroll
    for (int off = 32; off > 0; off >>= 1) {
        s += __shfl_xor(s, off, 64);
        ss += __shfl_xor(ss, off, 64);
    }
    const float mean = s * (1.f / 128.f);
    const float var = ss * (1.f / 128.f) - mean * mean;
    const float rstd = rsqrtf(fmaxf(var, 0.f) + 1e-6f);
    const float2 gv = *(const float2*)(ln_g + lane * 2);
    const float2 lbv = *(const float2*)(ln_b + lane * 2);
    const float y0 = (a0 - mean) * rstd * gv.x + lbv.x;
    const float y1 = (a1 - mean) * rstd * gv.y + lbv.y;
    *(u32*)(xln + (size_t)site * 128 + lane * 2) = (u32)f2bf(y0) | ((u32)f2bf(y1) << 16);
}

// ---------------------------------------------------------------------------
// w1 fp32 [128,512] -> w1t bf16 [512,128] (B^T layout for MFMA B-frag reads)
// ---------------------------------------------------------------------------
__global__ __launch_bounds__(256) void transpose_w1_k(
    const float* __restrict__ w1, u16* __restrict__ w1t)
{
    const int e = blockIdx.x * 256 + threadIdx.x;    // 65536 total
    const int n = e >> 7, k = e & 127;
    w1t[e] = f2bf(w1[k * 512 + n]);
}

// ---------------------------------------------------------------------------
// Kernel B: h = gelu(xln @ w1 + b1)  [N,512] bf16  + per-channel sum(h^2).
// One block per 128-row M-tile; A staged ONCE in 32 KB LDS; loop over 4
// N-tiles barrier-free with B frags read directly from L2-resident w1t.
// ---------------------------------------------------------------------------
__global__ __launch_bounds__(256, 3) void gemm1_k(
    const u16* __restrict__ xln, const u16* __restrict__ w1t,
    const float* __restrict__ b1, u16* __restrict__ h,
    float* __restrict__ gx_sq, int nsites)
{
    __shared__ uint4 sA[2048];   // 32 KB
    __shared__ float s_red[512];
    const int t = threadIdx.x;
    const int m0 = blockIdx.x * 128;
    #pragma unroll
    for (int it = 0; it < 8; ++it) {
        const int e = it * 256 + t;
        const int r = e >> 4, c = e & 15;
        uint4 va = {0u, 0u, 0u, 0u};
        const int rowg = m0 + r;
        if (rowg < nsites) va = *(const uint4*)(xln + (size_t)rowg * 128 + c * 8);
        sA[sw_idx(r, c)] = va;
    }
    s_red[t] = 0.f;
    s_red[t + 256] = 0.f;
    __syncthreads();
    const int lane = t & 63;
    const int w = t >> 6;
    const int wm = (w >> 1) * 64, wn = (w & 1) * 64;
    const int l15 = lane & 15, quad = lane >> 4;
    for (int j = 0; j < 4; ++j) {
        const int n0 = j * 128;
        f32x4 acc[4][4];
        #pragma unroll
        for (int i = 0; i < 4; ++i)
            #pragma unroll
            for (int jj = 0; jj < 4; ++jj) acc[i][jj] = f32x4{0.f, 0.f, 0.f, 0.f};
        #pragma unroll
        for (int kk = 0; kk < 4; ++kk) {
            const int cq = kk * 4 + quad;
            bf16x8 a[4], b[4];
            #pragma unroll
            for (int mt = 0; mt < 4; ++mt) a[mt] = *(const bf16x8*)&sA[sw_idx(wm + mt * 16 + l15, cq)];
            #pragma unroll
            for (int nt = 0; nt < 4; ++nt)
                b[nt] = *(const bf16x8*)(w1t + (size_t)(n0 + wn + nt * 16 + l15) * 128 + cq * 8);
            #pragma unroll
            for (int mt = 0; mt < 4; ++mt)
                #pragma unroll
                for (int nt = 0; nt < 4; ++nt)
                    acc[mt][nt] = __builtin_amdgcn_mfma_f32_16x16x32_bf16(a[mt], b[nt], acc[mt][nt], 0, 0, 0);
        }
        float ssl[4] = {0.f, 0.f, 0.f, 0.f};
        float bias[4]; int col[4];
        #pragma unroll
        for (int nt = 0; nt < 4; ++nt) {
            col[nt] = n0 + wn + nt * 16 + l15;
            bias[nt] = b1[col[nt]];
        }
        #pragma unroll
        for (int mt = 0; mt < 4; ++mt) {
            const int rbase = m0 + wm + mt * 16 + quad * 4;
            #pragma unroll
            for (int nt = 0; nt < 4; ++nt) {
                #pragma unroll
                for (int rg = 0; rg < 4; ++rg) {
                    const int rowg = rbase + rg;
                    if (rowg < nsites) {
                        const float v = fast_gelu(acc[mt][nt][rg] + bias[nt]);
                        h[(size_t)rowg * 512 + col[nt]] = f2bf(v);
                        ssl[nt] += v * v;
                    }
                }
            }
        }
        #pragma unroll
        for (int nt = 0; nt < 4; ++nt) atomicAdd(&s_red[col[nt]], ssl[nt]);
    }
    __syncthreads();
    atomicAdd(&gx_sq[t], s_red[t]);
    atomicAdd(&gx_sq[t + 256], s_red[t + 256]);
}

// ---------------------------------------------------------------------------
// Kernel C1: GRN scale + effective bias (one block, cooperative).
// scale[c] = grn_g[c]*nx[c] + 1;  b_eff = b2 + grn_b @ w2.
// ---------------------------------------------------------------------------
__global__ __launch_bounds__(512) void grn_scale_k(
    const float* __restrict__ gx_sq, const float* __restrict__ grn_g,
    const float* __restrict__ grn_b, const float* __restrict__ w2,
    const float* __restrict__ b2, float* __restrict__ scale, float* __restrict__ b_eff)
{
    __shared__ float red[512];
    __shared__ float redb[512];
    const int t = threadIdx.x;
    const float g = sqrtf(gx_sq[t]);
    red[t] = g;
    __syncthreads();
    #pragma unroll
    for (int off = 256; off > 0; off >>= 1) {
        if (t < off) red[t] += red[t + off];
        __syncthreads();
    }
    const float mean = red[0] * (1.f / 512.f);
    scale[t] = grn_g[t] * (g / (mean + 1e-6f)) + 1.f;
    const int dc = t & 127, grp = t >> 7;
    float p = 0.f;
    #pragma unroll 8
    for (int i = 0; i < 128; ++i) {
        const int c = grp * 128 + i;
        p += grn_b[c] * w2[(size_t)c * 128 + dc];
    }
    redb[t] = p;
    __syncthreads();
    if (t < 128) b_eff[t] = b2[t] + redb[t] + redb[t + 128] + redb[t + 256] + redb[t + 384];
}

// ---------------------------------------------------------------------------
// Kernel C2: w2t[dc][c] = bf16(scale[c] * w2[c][dc])  (coalesced writes)
// ---------------------------------------------------------------------------
__global__ __launch_bounds__(256) void w2t_k(
    const float* __restrict__ scale, const float* __restrict__ w2,
    u16* __restrict__ w2t)
{
    const int e = blockIdx.x * 256 + threadIdx.x;    // 65536
    const int c = e & 511, dc = e >> 9;
    w2t[e] = f2bf(scale[c] * w2[(size_t)c * 128 + dc]);
}

// ---------------------------------------------------------------------------
// Kernel D: out = feats + h_scaled @ w2 + b_eff (fp32 out).  M-tile 128,
// N=128, K=512 in 4 staged 32 KB chunks; B frags from L2-resident w2t.
// ---------------------------------------------------------------------------
__global__ __launch_bounds__(256, 3) void gemm2_k(
    const u16* __restrict__ h, const u16* __restrict__ w2t,
    const float* __restrict__ b_eff, const float* __restrict__ feats,
    float* __restrict__ out, int nsites)
{
    __shared__ uint4 sA[2048];   // 32 KB
    const int t = threadIdx.x;
    const int m0 = blockIdx.x * 128;
    const int lane = t & 63;
    const int w = t >> 6;
    const int wm = (w >> 1) * 64, wn = (w & 1) * 64;
    const int l15 = lane & 15, quad = lane >> 4;
    f32x4 acc[4][4];
    #pragma unroll
    for (int i = 0; i < 4; ++i)
        #pragma unroll
        for (int j = 0; j < 4; ++j) acc[i][j] = f32x4{0.f, 0.f, 0.f, 0.f};
    for (int kc = 0; kc < 4; ++kc) {
        const int kbase = kc * 128;
        if (kc) __syncthreads();
        #pragma unroll
        for (int it = 0; it < 8; ++it) {
            const int e = it * 256 + t;
            const int r = e >> 4, c = e & 15;
            uint4 va = {0u, 0u, 0u, 0u};
            const int rowg = m0 + r;
            if (rowg < nsites) va = *(const uint4*)(h + (size_t)rowg * 512 + kbase + c * 8);
            sA[sw_idx(r, c)] = va;
        }
        __syncthreads();
        #pragma unroll
        for (int kk = 0; kk < 4; ++kk) {
            const int cq = kk * 4 + quad;
            bf16x8 a[4], b[4];
            #pragma unroll
            for (int mt = 0; mt < 4; ++mt) a[mt] = *(const bf16x8*)&sA[sw_idx(wm + mt * 16 + l15, cq)];
            #pragma unroll
            for (int nt = 0; nt < 4; ++nt)
                b[nt] = *(const bf16x8*)(w2t + (size_t)(wn + nt * 16 + l15) * 512 + kbase + cq * 8);
            #pragma unroll
            for (int mt = 0; mt < 4; ++mt)
                #pragma unroll
                for (int nt = 0; nt < 4; ++nt)
                    acc[mt][nt] = __builtin_amdgcn_mfma_f32_16x16x32_bf16(a[mt], b[nt], acc[mt][nt], 0, 0, 0);
        }
    }
    float be[4]; int col[4];
    #pragma unroll
    for (int nt = 0; nt < 4; ++nt) {
        col[nt] = wn + nt * 16 + l15;
        be[nt] = b_eff[col[nt]];
    }
    #pragma unroll
    for (int mt = 0; mt < 4; ++mt) {
        const int rbase = m0 + wm + mt * 16 + quad * 4;
        #pragma unroll
        for (int nt = 0; nt < 4; ++nt) {
            #pragma unroll
            for (int rg = 0; rg < 4; ++rg) {
                const int rowg = rbase + rg;
                if (rowg < nsites) {
                    out[(size_t)rowg * 128 + col[nt]] =
                        acc[mt][nt][rg] + be[nt] + feats[(size_t)rowg * 128 + col[nt]];
                }
            }
        }
    }
}

// ---------------------------------------------------------------------------
extern "C" void kernel_launch(void* const* d_in, const int* in_sizes, int n_in,
                              void* d_out, int out_size, void* d_ws, size_t ws_size,
                              hipStream_t stream) {
    const float* feats = (const float*)d_in[0];    // [N,128] f32
    const int* nb      = (const int*)d_in[1];      // [N,343] int32
    const float* dw_w  = (const float*)d_in[2];    // [343,128] f32
    const float* dw_b  = (const float*)d_in[3];    // [128]
    const float* ln_g  = (const float*)d_in[4];    // [128]
    const float* ln_b  = (const float*)d_in[5];    // [128]
    const float* w1    = (const float*)d_in[6];    // [128,512]
    const float* b1    = (const float*)d_in[7];    // [512]
    const float* grn_g = (const float*)d_in[8];    // [512]
    const float* grn_b = (const float*)d_in[9];    // [512]
    const float* w2    = (const float*)d_in[10];   // [512,128]
    const float* b2    = (const float*)d_in[11];   // [128]
    float* out = (float*)d_out;
    const int nsites = in_sizes[0] / 128;

    char* ws = (char*)d_ws;
    size_t off = 0;
    u16* xln   = (u16*)(ws + off);  off += (((size_t)nsites * 128 * 2) + 255) & ~(size_t)255;
    u16* h     = (u16*)(ws + off);  off += (((size_t)nsites * 512 * 2) + 255) & ~(size_t)255;
    u16* featsb= (u16*)(ws + off);  off += (((size_t)nsites * 128 * 2) + 255) & ~(size_t)255;
    u16* dwwb  = (u16*)(ws + off);  off += 343 * 128 * 2 + 128;
    u16* w1t   = (u16*)(ws + off);  off += 512 * 128 * 2;
    u16* w2t   = (u16*)(ws + off);  off += 128 * 512 * 2;
    float* gx_sq = (float*)(ws + off); off += 512 * 4;
    float* scale = (float*)(ws + off); off += 512 * 4;
    float* b_eff = (float*)(ws + off); off += 128 * 4;

    hipMemsetAsync(gx_sq, 0, 512 * sizeof(float), stream);
    const int nfeat4 = nsites * 32;                 // feats elements / 4
    cast_feats_k<<<(nfeat4 + 255) / 256, 256, 0, stream>>>(feats, featsb, nfeat4);
    const int ndww4 = 343 * 32;                     // dw_w elements / 4
    cast_feats_k<<<(ndww4 + 255) / 256, 256, 0, stream>>>(dw_w, dwwb, ndww4);
    transpose_w1_k<<<256, 256, 0, stream>>>(w1, w1t);
    dwln_k<<<(nsites + 3) / 4, 256, 0, stream>>>(featsb, nb, dwwb, dw_b, ln_g, ln_b, xln, nsites);
    const int mblocks = (nsites + 127) / 128;
    gemm1_k<<<mblocks, 256, 0, stream>>>(xln, w1t, b1, h, gx_sq, nsites);
    grn_scale_k<<<1, 512, 0, stream>>>(gx_sq, grn_g, grn_b, w2, b2, scale, b_eff);
    w2t_k<<<256, 256, 0, stream>>>(scale, w2, w2t);
    gemm2_k<<<mblocks, 256, 0, stream>>>(h, w2t, b_eff, feats, out, nsites);
}